// Round 4
// baseline (361.120 us; speedup 1.0000x reference)
//
#include <hip/hip_runtime.h>

// SelfAttention: x(8,2048,768) fp32, W_q/W_k/W_v (768,768) fp32 -> H fp32.
// f16 MFMA pipeline, fused softmax:
//   cvt -> gemm<0> Q(scaled),K -> gemm<3> Vt -> gemm<1> P'=exp(S)+rowsums
//       -> gemm<2> H = (P'@Vt^T) * 1/rowsum
// This round: 256x128 block tile, 4 waves of 128x64, mfma_f32_32x32x16_f16
// (higher rate + half the LDS bytes/FLOP of 64x64 wave tiles), BK=64,
// XOR-swizzled LDS, global_load_lds(16B), LDS-staged coalesced epilogues.

typedef _Float16 f16;
typedef __attribute__((ext_vector_type(4))) _Float16 f16x4;
typedef __attribute__((ext_vector_type(8))) _Float16 f16x8;
typedef __attribute__((ext_vector_type(4))) float    f32x4;
typedef __attribute__((ext_vector_type(16))) float   f32x16;

#define BM 256
#define BN 128
#define BKH 64                      // K-tile in halfs (128 B rows)

#define SEQ   2048
#define DIM   768
#define NBAT  8
#define MTOT  (NBAT * SEQ)          // 16384
#define XN    ((long)MTOT * DIM)    // 12582912
#define WN    (DIM * DIM)           // 589824
#define SB    ((long)SEQ * SEQ)
#define QB    ((long)SEQ * DIM)
#define XN4   3145728               // XN/4
#define WN4   147456                // WN/4

__device__ __forceinline__ void async_cp16(const void* g, void* l) {
  __builtin_amdgcn_global_load_lds((__attribute__((address_space(1))) void*)g,
                                   (__attribute__((address_space(3))) void*)l,
                                   16, 0, 0);
}

// fp32 -> f16 for x and the three weights, one launch.
__global__ void cvt_all(const float* __restrict__ x, const float* __restrict__ wq,
                        const float* __restrict__ wk, const float* __restrict__ wv,
                        f16* __restrict__ out) {
  int i = blockIdx.x * 256 + threadIdx.x;      // float4 index
  const float* src; f16* dst; int idx;
  if (i < XN4) { src = x; dst = out; idx = i; }
  else {
    int j = i - XN4;
    int w = (j < WN4) ? 0 : (j < 2 * WN4) ? 1 : 2;
    idx = j - w * WN4;
    src = (w == 0) ? wq : (w == 1) ? wk : wv;
    dst = out + XN + (long)w * WN;
  }
  float4 v = ((const float4*)src)[idx];
  f16x4 o = {(f16)v.x, (f16)v.y, (f16)v.z, (f16)v.w};
  ((f16x4*)dst)[idx] = o;
}

// NT GEMM: C[m][n] = sum_k A[m][k]*B[n][k].  Block tile 256x128, 4 waves,
// wave tile 128(m) x 64(n) as 4x2 grid of 32x32x16 MFMAs.
// SWAP=true: mfma(bf,af) -> lane&31 = m, regs = n quads.
// SWAP=false (MODE 3): mfma(af,bf) -> lane&31 = n, regs = m quads.
// MODE 0: f16 row-major out (Q,K; z selects W/C plane; z==0 scaled).
// MODE 1: f16 out = exp(acc); rowsum partials -> Rsum[z*16 + by][2048].
// MODE 2: fp32 out = acc * (1/rowsum) from Rsum partials.
// MODE 3: f16 transposed out Vt[b][n][m-local].
template <int MODE, bool SWAP>
__global__ __launch_bounds__(256, 2)
void gemm_nt(const f16* __restrict__ Abase, long sAz,
             const f16* __restrict__ Bbase, long sBz,
             void* __restrict__ Cbase, long sCz,
             float* __restrict__ Rsum,
             int N, int K, float scale)
{
  __shared__ __align__(16) char smem[49152];   // lA 32KB + lB 16KB; epilogue aliases
  __shared__ float sRed[2][256];               // MODE1 cross-wave rowsum
  __shared__ float sinv[256];                  // MODE2 per-row 1/rowsum
  f16* lA = (f16*)smem;                        // [256][64] halfs
  f16* lB = (f16*)(smem + 32768);              // [128][64] halfs

  const int tid  = threadIdx.x;
  const int z    = blockIdx.z;
  const int m0   = blockIdx.x * BM;
  const int n0   = blockIdx.y * BN;
  const int wave = tid >> 6;
  const int lane = tid & 63;
  const int wm   = (wave & 1) * 128;
  const int wn   = (wave >> 1) * 64;
  const int l31  = lane & 31;
  const int q    = lane >> 5;

  const f16* A = Abase + (long)z * sAz;
  const f16* B = Bbase + (long)z * sBz;

  f32x16 acc[4][2] = {};

  if constexpr (MODE == 2) {
    // 1/rowsum for this block's 256 rows from 16 per-128col partials.
    const float* rp = Rsum + (long)z * 16 * SEQ + m0 + tid;
    float s = 0.f;
#pragma unroll
    for (int k = 0; k < 16; ++k) s += rp[k * SEQ];
    sinv[tid] = 1.0f / s;
    // first k-loop __syncthreads orders this before epilogue reads
  }

  // staging: thread t loads 16B chunks; slot = pass*256 + tid; row = slot>>3,
  // stored chunk = slot&7, global chunk = stored ^ (row&7).
  const int srow = tid >> 3;                      // 0..31 within 32-row group
  const int cg   = ((tid & 7) ^ (srow & 7)) * 8;  // global k-offset (halfs)
  const f16* gA = A + (long)(m0 + srow) * K + cg;
  const f16* gB = B + (long)(n0 + srow) * K + cg;
  f16* la = lA + tid * 8;
  f16* lb = lB + tid * 8;

  // fragment addressing: row (wm + i*32 + l31), chunk ((2s+q) ^ (l31&7))
  const int swz = lane & 7;
  const int aro = (wm + l31) * BKH;
  const int bro = (wn + l31) * BKH;

  for (int k0 = 0; k0 < K; k0 += BKH) {
#pragma unroll
    for (int i = 0; i < 8; ++i)
      async_cp16(gA + (long)(i * 32) * K + k0, la + i * 2048);
#pragma unroll
    for (int j = 0; j < 4; ++j)
      async_cp16(gB + (long)(j * 32) * K + k0, lb + j * 2048);
    __syncthreads();
#pragma unroll
    for (int s = 0; s < 4; ++s) {
      const int co = ((2 * s + q) ^ swz) * 8;
      f16x8 af[4], bf[2];
#pragma unroll
      for (int i = 0; i < 4; ++i) af[i] = *(const f16x8*)&lA[aro + i * 2048 + co];
#pragma unroll
      for (int j = 0; j < 2; ++j) bf[j] = *(const f16x8*)&lB[bro + j * 2048 + co];
#pragma unroll
      for (int i = 0; i < 4; ++i)
#pragma unroll
        for (int j = 0; j < 2; ++j)
          acc[i][j] = SWAP
            ? __builtin_amdgcn_mfma_f32_32x32x16_f16(bf[j], af[i], acc[i][j], 0, 0, 0)
            : __builtin_amdgcn_mfma_f32_32x32x16_f16(af[i], bf[j], acc[i][j], 0, 0, 0);
    }
    __syncthreads();
  }

  if constexpr (MODE == 0 || MODE == 1) {
    // SWAP: lane&31 = m (row wm + i*32 + l31); element e: n = wn + j*32 +
    // (e&3) + 8*(e>>2) + 4*q.  Stage 128 rows/pass into T[128][136].
    const int TS = 136;
    f16* T = (f16*)smem;
    const float sc = (MODE == 0 && z == 0) ? scale : 1.0f;
    float rs[4] = {0.f, 0.f, 0.f, 0.f};
    for (int p = 0; p < 2; ++p) {
      if ((wave & 1) == p) {
#pragma unroll
        for (int i = 0; i < 4; ++i)
#pragma unroll
          for (int j = 0; j < 2; ++j)
#pragma unroll
            for (int rq = 0; rq < 4; ++rq) {
              f16x4 v;
#pragma unroll
              for (int t = 0; t < 4; ++t) {
                float xv = acc[i][j][rq * 4 + t];
                xv = (MODE == 1) ? __expf(xv) : xv * sc;
                v[t] = (f16)xv;
                if (MODE == 1) rs[i] += (float)v[t];
              }
              *(f16x4*)&T[(i * 32 + l31) * TS + wn + j * 32 + rq * 8 + q * 4] = v;
            }
        if constexpr (MODE == 1) {
#pragma unroll
          for (int i = 0; i < 4; ++i) {
            rs[i] += __shfl_xor(rs[i], 32);          // combine q halves
            if (q == 0) sRed[wave >> 1][wm + i * 32 + l31] = rs[i];
          }
        }
      }
      __syncthreads();
      const int row = tid >> 1, seg = (tid & 1) * 64;
      f16* C = (f16*)Cbase + (long)z * sCz;
#pragma unroll
      for (int k = 0; k < 8; ++k) {
        f16x8 v = *(const f16x8*)&T[row * TS + seg + k * 8];
        *(f16x8*)&C[(long)(m0 + p * 128 + row) * N + n0 + seg + k * 8] = v;
      }
      if (p == 0) __syncthreads();
    }
    if constexpr (MODE == 1) {
      // sRed fully written before the last pre-store barrier
      float s = sRed[0][tid] + sRed[1][tid];
      Rsum[((long)z * 16 + blockIdx.y) * SEQ + m0 + tid] = s;
    }
  }

  if constexpr (MODE == 3) {
    // SWAP=false: lane&31 = n; element e: m = wm + i*32 + (e&3)+8*(e>>2)+4q.
    // Stage T[64 n][264 m] per wn-half; store Vt[b][d][s] coalesced in s.
    const int MS = 264;
    f16* T = (f16*)smem;
    const int b = m0 >> 11, sl = m0 & 2047;
    for (int p = 0; p < 2; ++p) {
      if ((wave >> 1) == p) {
#pragma unroll
        for (int i = 0; i < 4; ++i)
#pragma unroll
          for (int j = 0; j < 2; ++j)
#pragma unroll
            for (int rq = 0; rq < 4; ++rq) {
              f16x4 v = {(f16)acc[i][j][rq * 4 + 0], (f16)acc[i][j][rq * 4 + 1],
                         (f16)acc[i][j][rq * 4 + 2], (f16)acc[i][j][rq * 4 + 3]};
              *(f16x4*)&T[(j * 32 + l31) * MS + wm + i * 32 + rq * 8 + q * 4] = v;
            }
      }
      __syncthreads();
      const int row = tid >> 2, cs = (tid & 3) * 64;
      f16* C = (f16*)Cbase;
#pragma unroll
      for (int k = 0; k < 8; ++k) {
        f16x8 v = *(const f16x8*)&T[row * MS + cs + k * 8];
        *(f16x8*)&C[(long)b * QB + (long)(n0 + p * 64 + row) * SEQ + sl + cs + k * 8] = v;
      }
      if (p == 0) __syncthreads();
    }
  }

  if constexpr (MODE == 2) {
    // fp32 normalized out; 4 passes of 64 rows through Tf[64][132].
    const int FS = 132;
    float* Tf = (float*)smem;
    float* C = (float*)Cbase + (long)z * sCz;
    for (int p = 0; p < 4; ++p) {
      if ((wave & 1) == (p >> 1)) {
        const int ib = (p & 1) * 2;
#pragma unroll
        for (int ii = 0; ii < 2; ++ii) {
          const int i = ib + ii;
          const float iv = sinv[wm + i * 32 + l31];
#pragma unroll
          for (int j = 0; j < 2; ++j)
#pragma unroll
            for (int rq = 0; rq < 4; ++rq) {
              f32x4 v = {acc[i][j][rq * 4 + 0] * iv, acc[i][j][rq * 4 + 1] * iv,
                         acc[i][j][rq * 4 + 2] * iv, acc[i][j][rq * 4 + 3] * iv};
              *(f32x4*)&Tf[(ii * 32 + l31) * FS + wn + j * 32 + rq * 8 + q * 4] = v;
            }
        }
      }
      __syncthreads();
      const int row = tid >> 2, cs = (tid & 3) * 32;
#pragma unroll
      for (int k = 0; k < 8; ++k) {
        f32x4 v = *(const f32x4*)&Tf[row * FS + cs + k * 4];
        *(f32x4*)&C[(long)(m0 + p * 64 + row) * N + n0 + cs + k * 4] = v;
      }
      if (p < 3) __syncthreads();
    }
  }
}

extern "C" void kernel_launch(void* const* d_in, const int* in_sizes, int n_in,
                              void* d_out, int out_size, void* d_ws, size_t ws_size,
                              hipStream_t stream) {
  const float* x  = (const float*)d_in[0];
  const float* Wq = (const float*)d_in[1];
  const float* Wk = (const float*)d_in[2];
  const float* Wv = (const float*)d_in[3];

  f16* ws   = (f16*)d_ws;
  f16* x16  = ws;                  // XN
  f16* W16  = x16 + XN;            // 3*WN
  f16* Q16  = W16 + 3L * WN;       // XN  (pre-scaled by 1/sqrt(768))
  f16* K16  = Q16 + XN;            // XN
  f16* Vt16 = K16 + XN;            // XN   [b][d][s]
  f16* S16  = Vt16 + XN;           // NBAT*SB  (exp scores, unnormalized)
  float* rsumP = (float*)(S16 + (long)NBAT * SB);   // [8][16][2048] f32 partials

  cvt_all<<<14016, 256, 0, stream>>>(x, Wq, Wk, Wv, ws);

  dim3 blk(256);
  // Q (scaled), K projections: z in {0,1}
  gemm_nt<0, true><<<dim3(MTOT / BM, DIM / BN, 2), blk, 0, stream>>>(
      x16, 0L, W16, (long)WN, (void*)Q16, XN, nullptr, DIM, DIM, 0.03608439182435161f);
  // V projection, transposed out
  gemm_nt<3, false><<<dim3(MTOT / BM, DIM / BN, 1), blk, 0, stream>>>(
      x16, 0L, W16 + 2L * WN, 0L, (void*)Vt16, 0L, nullptr, DIM, DIM, 1.0f);
  // P' = exp(QK^T) (Q pre-scaled), f16, unnormalized + rowsum partials
  gemm_nt<1, true><<<dim3(SEQ / BM, SEQ / BN, NBAT), blk, 0, stream>>>(
      Q16, QB, K16, QB, (void*)S16, SB, rsumP, SEQ, DIM, 1.0f);
  // H = (P' @ Vt^T) / rowsum, fp32
  gemm_nt<2, true><<<dim3(SEQ / BM, DIM / BN, NBAT), blk, 0, stream>>>(
      S16, SB, Vt16, QB, d_out, QB, rsumP, DIM, SEQ, 1.0f);
}

// Round 5
// 355.183 us; speedup vs baseline: 1.0167x; 1.0167x over previous
//
#include <hip/hip_runtime.h>

// SelfAttention: x(8,2048,768) fp32, W_q/W_k/W_v (768,768) fp32 -> H fp32.
// Algebraic rewrite: S = x (Wq^T Wk / sqrt(D)) x^T, so:
//   cvt(x,Wv) ; transpose(Wq,Wk) ; G2[e][d] = sum_k Wk[k][e] Wq[k][d] * scale
//   T~ = x @ G2^T(NT) ; Vt = (x@Wv^T)^T ; P' = exp(T~ x^T) + rowsums ; H = P'V/rowsum
// GEMM: 128x128 tile, 16x16x32 f16 MFMA, BK=32, double-buffered LDS with ONE
// barrier per K-iter (DMA for iter k+1 in flight during compute of iter k),
// bank-swizzled (slot = chunk ^ ((row>>1)&3)), global_load_lds(16B) staging,
// LDS-staged coalesced epilogues.

typedef _Float16 f16;
typedef __attribute__((ext_vector_type(4))) _Float16 f16x4;
typedef __attribute__((ext_vector_type(8))) _Float16 f16x8;
typedef __attribute__((ext_vector_type(4))) float    f32x4;

#define BM 128
#define BN 128
#define BKH 32                      // K-tile in halfs (64 B rows), per buffer

#define SEQ   2048
#define DIM   768
#define NBAT  8
#define MTOT  (NBAT * SEQ)          // 16384
#define XN    ((long)MTOT * DIM)    // 12582912
#define WN    (DIM * DIM)           // 589824
#define SB    ((long)SEQ * SEQ)
#define QB    ((long)SEQ * DIM)
#define XN4   3145728               // XN/4
#define WN4   147456                // WN/4

__device__ __forceinline__ void async_cp16(const void* g, void* l) {
  __builtin_amdgcn_global_load_lds((__attribute__((address_space(1))) void*)g,
                                   (__attribute__((address_space(3))) void*)l,
                                   16, 0, 0);
}

// fp32 -> f16 for x and Wv.
__global__ void cvt_all(const float* __restrict__ x, const float* __restrict__ wv,
                        f16* __restrict__ x16, f16* __restrict__ wv16) {
  int i = blockIdx.x * 256 + threadIdx.x;      // float4 index
  const float* src; f16* dst; int idx;
  if (i < XN4) { src = x; dst = x16; idx = i; }
  else { src = wv; dst = wv16; idx = i - XN4; }
  float4 v = ((const float4*)src)[idx];
  f16x4 o = {(f16)v.x, (f16)v.y, (f16)v.z, (f16)v.w};
  ((f16x4*)dst)[idx] = o;
}

// Wq,Wk fp32 -> transposed f16 (WT[d][k] = W[k][d]).
__global__ void transpose_w(const float* __restrict__ wq, const float* __restrict__ wk,
                            f16* __restrict__ wqt, f16* __restrict__ wkt) {
  __shared__ float t[32][33];
  const float* src = blockIdx.z ? wk : wq;
  f16* dst = blockIdx.z ? wkt : wqt;
  const int bx = blockIdx.x * 32, by = blockIdx.y * 32;
  const int tx = threadIdx.x & 31, ty = threadIdx.x >> 5;   // 32 x 8
#pragma unroll
  for (int r = 0; r < 4; ++r)
    t[ty + 8 * r][tx] = src[(long)(by + ty + 8 * r) * DIM + bx + tx];
  __syncthreads();
#pragma unroll
  for (int r = 0; r < 4; ++r)
    dst[(long)(bx + ty + 8 * r) * DIM + by + tx] = (f16)t[tx][ty + 8 * r];
}

// NT GEMM: C[m][n] = sum_k A[m][k]*B[n][k].  128x128 block, 4 waves of 64x64.
// MODE 0: f16 row-major out; z==0 scaled by `scale` (used for G2 and T~).
// MODE 1: f16 out = exp(acc); rowsum partials -> Rsum[z][32][2048].
// MODE 2: fp32 out = acc * (1/rowsum) from Rsum partials.
// MODE 3: f16 transposed out Vt[b][n][m-local]. SWAP=false.
// SWAP=true: mfma(bf,af): lane&15 = m, regs = 4 consecutive n.
// SWAP=false: lane&15 = n, regs = 4 consecutive m.
template <int MODE, bool SWAP>
__global__ __launch_bounds__(256, 4)
void gemm_nt(const f16* __restrict__ Abase, long sAz,
             const f16* __restrict__ Bbase, long sBz,
             void* __restrict__ Cbase, long sCz,
             float* __restrict__ Rsum,
             int N, int K, float scale)
{
  // two 16 KB staging buffers (each: lA[128][32] + lB[128][32]); epilogue aliases
  __shared__ __align__(16) char smem[34816];
  __shared__ float sinv[128];                  // MODE2 per-row 1/rowsum

  const int tid  = threadIdx.x;
  const int z    = blockIdx.z;
  const int m0   = blockIdx.x * BM;
  const int n0   = blockIdx.y * BN;
  const int wave = tid >> 6;
  const int lane = tid & 63;
  const int wm   = (wave & 1) * 64;
  const int wn   = (wave >> 1) * 64;

  const f16* A = Abase + (long)z * sAz;
  const f16* B = Bbase + (long)z * sBz;

  f32x4 acc[4][4] = {};

  if constexpr (MODE == 2) {
    if (tid < 128) {
      const float* rp = Rsum + (long)z * 32 * SEQ + m0 + tid;
      float s = 0.f;
#pragma unroll
      for (int k = 0; k < 32; ++k) s += rp[k * SEQ];
      sinv[tid] = 1.0f / s;
    }
    // ordered by first in-loop __syncthreads
  }

  // Staging: LDS slot (16B) index within region = tid (c=0) / 256+tid (c=1).
  // row = slot>>2, stored slot s = slot&3, global chunk = s ^ ((row>>1)&3).
  const int srow = tid >> 2;                          // 0..63
  const int gc   = ((tid & 3) ^ ((tid >> 3) & 3)) * 8; // global k-offset (halfs)
  const f16* gA0 = A + (long)(m0 + srow) * K + gc;
  const f16* gA1 = gA0 + 64L * K;
  const f16* gB0 = B + (long)(n0 + srow) * K + gc;
  const f16* gB1 = gB0 + 64L * K;

#define STAGE(bufp, kk)  do { f16* _d = (f16*)(bufp); \
    async_cp16(gA0 + (kk), _d + tid * 8); \
    async_cp16(gA1 + (kk), _d + 2048 + tid * 8); \
    async_cp16(gB0 + (kk), _d + 4096 + tid * 8); \
    async_cp16(gB1 + (kk), _d + 6144 + tid * 8); } while (0)

  // Fragment read addressing: global chunk q of row r at slot q ^ ((r>>1)&3).
  const int frow = lane & 15;
  const int q    = lane >> 4;                  // global k-chunk 0..3
  const int co   = (q ^ ((frow >> 1) & 3)) * 8;
  const int aro  = (wm + frow) * BKH;
  const int bro  = 4096 + (wn + frow) * BKH;

  const int iters = K >> 5;
  STAGE(smem, 0);
  for (int it = 0; it < iters; ++it) {
    f16* cur = (f16*)(smem + (it & 1) * 16384);
    f16* nxt = (f16*)(smem + ((it + 1) & 1) * 16384);
    __syncthreads();   // drains DMA into cur (in flight since prev iter)
    if (it + 1 < iters) STAGE(nxt, (it + 1) << 5);
    f16x8 af[4], bf[4];
#pragma unroll
    for (int i = 0; i < 4; ++i) af[i] = *(const f16x8*)&cur[aro + i * 512 + co];
#pragma unroll
    for (int j = 0; j < 4; ++j) bf[j] = *(const f16x8*)&cur[bro + j * 512 + co];
#pragma unroll
    for (int i = 0; i < 4; ++i)
#pragma unroll
      for (int j = 0; j < 4; ++j)
        acc[i][j] = SWAP
          ? __builtin_amdgcn_mfma_f32_16x16x32_f16(bf[j], af[i], acc[i][j], 0, 0, 0)
          : __builtin_amdgcn_mfma_f32_16x16x32_f16(af[i], bf[j], acc[i][j], 0, 0, 0);
  }
  __syncthreads();   // all frag reads done before epilogue aliases smem

  const int TS = 136;  // f16 epilogue tile stride (halfs)

  if constexpr (MODE == 0 || MODE == 1) {
    f16* T = (f16*)smem;   // [128][TS]
    float rs[4] = {0.f, 0.f, 0.f, 0.f};
    const float sc = (MODE == 0 && z == 0) ? scale : 1.0f;
#pragma unroll
    for (int i = 0; i < 4; ++i)
#pragma unroll
      for (int j = 0; j < 4; ++j) {
        f16x4 v;
#pragma unroll
        for (int r = 0; r < 4; ++r) {
          float xv = acc[i][j][r];
          if (MODE == 1) xv = __expf(xv); else xv *= sc;
          v[r] = (f16)xv;
          if (MODE == 1) rs[i] += (float)v[r];   // sum of f16-rounded values
        }
        *(f16x4*)&T[(wm + i * 16 + frow) * TS + wn + j * 16 + q * 4] = v;
      }
    if constexpr (MODE == 1) {
#pragma unroll
      for (int i = 0; i < 4; ++i) {
        rs[i] += __shfl_xor(rs[i], 16);
        rs[i] += __shfl_xor(rs[i], 32);   // full 64-col segment sum
      }
      if (lane < 16) {   // q==0 lanes hold the reduced sums
        float* rp = Rsum + ((long)z * 32 + blockIdx.y * 2 + (wn >> 6)) * SEQ + m0 + wm;
#pragma unroll
        for (int i = 0; i < 4; ++i) rp[i * 16 + frow] = rs[i];
      }
    }
    __syncthreads();
    f16* C = (f16*)Cbase + (long)z * sCz;
    const int row = tid >> 1, seg = (tid & 1) * 64;
#pragma unroll
    for (int k = 0; k < 8; ++k) {
      f16x8 v = *(const f16x8*)&T[row * TS + seg + k * 8];
      *(f16x8*)&C[(long)(m0 + row) * N + n0 + seg + k * 8] = v;
    }
  }

  if constexpr (MODE == 3) {   // Vt[b][d][s]; SWAP=false: regs = consecutive m (=s)
    f16* T = (f16*)smem;       // [n(=d) 128][TS] holding m(=s) contiguous
#pragma unroll
    for (int i = 0; i < 4; ++i)
#pragma unroll
      for (int j = 0; j < 4; ++j) {
        f16x4 v = {(f16)acc[i][j][0], (f16)acc[i][j][1],
                   (f16)acc[i][j][2], (f16)acc[i][j][3]};
        *(f16x4*)&T[(wn + j * 16 + frow) * TS + wm + i * 16 + q * 4] = v;
      }
    __syncthreads();
    f16* C = (f16*)Cbase;
    const int b = m0 >> 11, sl = m0 & 2047;
    const int row = tid >> 1, seg = (tid & 1) * 64;
#pragma unroll
    for (int k = 0; k < 8; ++k) {
      f16x8 v = *(const f16x8*)&T[row * TS + seg + k * 8];
      *(f16x8*)&C[(long)b * QB + (long)(n0 + row) * SEQ + sl + seg + k * 8] = v;
    }
  }

  if constexpr (MODE == 2) {   // fp32 out, normalized; 2-pass (64 rows) epilogue
    float inv[4];
#pragma unroll
    for (int i = 0; i < 4; ++i) inv[i] = sinv[wm + i * 16 + frow];

    float* Tf = (float*)smem;   // [64][FS] fp32
    const int FS = 132;
    float* C = (float*)Cbase + (long)z * sCz;
    for (int pass = 0; pass < 2; ++pass) {
      if (wm == pass * 64) {
#pragma unroll
        for (int i = 0; i < 4; ++i)
#pragma unroll
          for (int j = 0; j < 4; ++j) {
            f32x4 v = acc[i][j] * inv[i];
            *(f32x4*)&Tf[(i * 16 + frow) * FS + wn + j * 16 + q * 4] = v;
          }
      }
      __syncthreads();
      const int row = tid >> 2, cs = (tid & 3) * 32;
#pragma unroll
      for (int k = 0; k < 8; ++k) {
        f32x4 v = *(const f32x4*)&Tf[row * FS + cs + k * 4];
        *(f32x4*)&C[(long)(m0 + pass * 64 + row) * N + n0 + cs + k * 4] = v;
      }
      if (pass == 0) __syncthreads();
    }
  }
#undef STAGE
}

extern "C" void kernel_launch(void* const* d_in, const int* in_sizes, int n_in,
                              void* d_out, int out_size, void* d_ws, size_t ws_size,
                              hipStream_t stream) {
  const float* x  = (const float*)d_in[0];
  const float* Wq = (const float*)d_in[1];
  const float* Wk = (const float*)d_in[2];
  const float* Wv = (const float*)d_in[3];

  f16* ws    = (f16*)d_ws;
  f16* x16   = ws;                  // XN
  f16* Wv16  = x16 + XN;            // WN
  f16* WqT16 = Wv16 + WN;           // WN
  f16* WkT16 = WqT16 + WN;          // WN
  f16* G2    = WkT16 + WN;          // WN   G2[e][d] = sum_k Wk[k][e]Wq[k][d] * scale
  f16* T16   = G2 + WN;             // XN   T~ = x @ G2^T
  f16* Vt16  = T16 + XN;            // XN   [b][d][s]
  f16* S16   = Vt16 + XN;           // NBAT*SB (exp scores, unnormalized)
  float* rsumP = (float*)(S16 + (long)NBAT * SB);   // [8][32][2048] partials

  cvt_all<<<(XN4 + WN4) / 256, 256, 0, stream>>>(x, Wv, x16, Wv16);
  transpose_w<<<dim3(24, 24, 2), 256, 0, stream>>>(Wq, Wk, WqT16, WkT16);

  dim3 blk(256);
  // G2 = NT(WkT, WqT) * 1/sqrt(768)  (768x768x768)
  gemm_nt<0, true><<<dim3(6, 6, 1), blk, 0, stream>>>(
      WkT16, 0L, WqT16, 0L, (void*)G2, 0L, nullptr, DIM, DIM, 0.03608439182435161f);
  // T~ = NT(x16, G2)  (16384x768x768)
  gemm_nt<0, true><<<dim3(MTOT / BM, DIM / BN, 1), blk, 0, stream>>>(
      x16, 0L, G2, 0L, (void*)T16, 0L, nullptr, DIM, DIM, 1.0f);
  // Vt = (x @ Wv^T)^T per batch  (16384x768x768, transposed out)
  gemm_nt<3, false><<<dim3(MTOT / BM, DIM / BN, 1), blk, 0, stream>>>(
      x16, 0L, Wv16, 0L, (void*)Vt16, 0L, nullptr, DIM, DIM, 1.0f);
  // P' = exp(T~ x^T) per batch + rowsum partials  (2048x2048x768 x8)
  gemm_nt<1, true><<<dim3(SEQ / BM, SEQ / BN, NBAT), blk, 0, stream>>>(
      T16, QB, x16, QB, (void*)S16, SB, rsumP, SEQ, DIM, 1.0f);
  // H = (P' @ Vt^T) / rowsum, fp32  (2048x768x2048 x8)
  gemm_nt<2, true><<<dim3(SEQ / BM, DIM / BN, NBAT), blk, 0, stream>>>(
      S16, SB, Vt16, QB, d_out, QB, rsumP, DIM, SEQ, 1.0f);
}

// Round 6
// 332.993 us; speedup vs baseline: 1.0845x; 1.0666x over previous
//
#include <hip/hip_runtime.h>

// SelfAttention: x(8,2048,768) fp32, W_q/W_k/W_v (768,768) fp32 -> H fp32.
// Algebraic rewrite: S = x (Wq^T Wk / sqrt(D)) x^T:
//   cvt(x,Wv) ; transpose(Wq,Wk) ; G2 = NT(WkT,WqT)*scale ; T~ = NT(x,G2)
//   Vt = (x@Wv^T)^T ; P' = exp(NT(T~,x)) + rowsums ; H = NT(P',Vt)/rowsum
// GEMM loop = R3's best-measured structure: 128x128 block, 4 waves of 64x64,
// 16x16x32 f16 MFMA, BK=64, two barriers/iter, chunk^(row&7) LDS swizzle,
// global_load_lds(16B) staging, LDS-staged coalesced epilogues, 4 blocks/CU.

typedef _Float16 f16;
typedef __attribute__((ext_vector_type(4))) _Float16 f16x4;
typedef __attribute__((ext_vector_type(8))) _Float16 f16x8;
typedef __attribute__((ext_vector_type(4))) float    f32x4;

#define BM 128
#define BN 128
#define BKH 64                      // K-tile in halfs (128 B rows)

#define SEQ   2048
#define DIM   768
#define NBAT  8
#define MTOT  (NBAT * SEQ)          // 16384
#define XN    ((long)MTOT * DIM)    // 12582912
#define WN    (DIM * DIM)           // 589824
#define SB    ((long)SEQ * SEQ)
#define QB    ((long)SEQ * DIM)
#define XN4   3145728               // XN/4
#define WN4   147456                // WN/4

__device__ __forceinline__ void async_cp16(const void* g, void* l) {
  __builtin_amdgcn_global_load_lds((__attribute__((address_space(1))) void*)g,
                                   (__attribute__((address_space(3))) void*)l,
                                   16, 0, 0);
}

// fp32 -> f16 for x and Wv.
__global__ void cvt_all(const float* __restrict__ x, const float* __restrict__ wv,
                        f16* __restrict__ x16, f16* __restrict__ wv16) {
  int i = blockIdx.x * 256 + threadIdx.x;      // float4 index
  const float* src; f16* dst; int idx;
  if (i < XN4) { src = x; dst = x16; idx = i; }
  else { src = wv; dst = wv16; idx = i - XN4; }
  float4 v = ((const float4*)src)[idx];
  f16x4 o = {(f16)v.x, (f16)v.y, (f16)v.z, (f16)v.w};
  ((f16x4*)dst)[idx] = o;
}

// Wq,Wk fp32 -> transposed f16 (WT[d][k] = W[k][d]).
__global__ void transpose_w(const float* __restrict__ wq, const float* __restrict__ wk,
                            f16* __restrict__ wqt, f16* __restrict__ wkt) {
  __shared__ float t[32][33];
  const float* src = blockIdx.z ? wk : wq;
  f16* dst = blockIdx.z ? wkt : wqt;
  const int bx = blockIdx.x * 32, by = blockIdx.y * 32;
  const int tx = threadIdx.x & 31, ty = threadIdx.x >> 5;   // 32 x 8
#pragma unroll
  for (int r = 0; r < 4; ++r)
    t[ty + 8 * r][tx] = src[(long)(by + ty + 8 * r) * DIM + bx + tx];
  __syncthreads();
#pragma unroll
  for (int r = 0; r < 4; ++r)
    dst[(long)(bx + ty + 8 * r) * DIM + by + tx] = (f16)t[tx][ty + 8 * r];
}

// NT GEMM: C[m][n] = sum_k A[m][k]*B[n][k].  128x128 block, 4 waves of 64x64.
// MODE 0: f16 row-major out; z==0 scaled by `scale` (used for G2 and T~).
// MODE 1: f16 out = exp(acc); rowsum partials -> Rsum[z][32][2048].
// MODE 2: fp32 out = acc * (1/rowsum) from Rsum partials.
// MODE 3: f16 transposed out Vt[b][n][m-local]. SWAP=false.
// SWAP=true: mfma(bf,af): lane&15 = m, regs = 4 consecutive n.
// SWAP=false: lane&15 = n, regs = 4 consecutive m.
template <int MODE, bool SWAP>
__global__ __launch_bounds__(256, 4)
void gemm_nt(const f16* __restrict__ Abase, long sAz,
             const f16* __restrict__ Bbase, long sBz,
             void* __restrict__ Cbase, long sCz,
             float* __restrict__ Rsum,
             int N, int K, float scale)
{
  __shared__ __align__(16) char smem[34816];   // 32 KB staging; epilogue aliases
  __shared__ float sinv[128];                  // MODE2 per-row 1/rowsum
  f16* lA = (f16*)smem;                        // [128][64] halfs
  f16* lB = (f16*)(smem + 16384);              // [128][64] halfs

  const int tid  = threadIdx.x;
  const int z    = blockIdx.z;
  const int m0   = blockIdx.x * BM;
  const int n0   = blockIdx.y * BN;
  const int wave = tid >> 6;
  const int lane = tid & 63;
  const int wm   = (wave & 1) * 64;
  const int wn   = (wave >> 1) * 64;

  const f16* A = Abase + (long)z * sAz;
  const f16* B = Bbase + (long)z * sBz;

  f32x4 acc[4][4] = {};

  if constexpr (MODE == 2) {
    if (tid < 128) {
      const float* rp = Rsum + (long)z * 32 * SEQ + m0 + tid;
      float s = 0.f;
#pragma unroll
      for (int k = 0; k < 32; ++k) s += rp[k * SEQ];
      sinv[tid] = 1.0f / s;
    }
    // ordered before epilogue reads by the in-loop barriers
  }

  // staging: thread t loads 16B: row srow (of 32-row group p), swizzled k-chunk.
  const int srow = tid >> 3;                         // 0..31
  const int gcol = ((tid & 7) ^ (srow & 7)) * 8;     // swizzle chunk by row&7
  const f16* ga = A + (long)(m0 + srow) * K + gcol;
  const f16* gb = B + (long)(n0 + srow) * K + gcol;
  f16* la = lA + tid * 8;
  f16* lb = lB + tid * 8;

  // MFMA fragment addressing: row = lane&15 (+16i +wm), k-chunk (s*4+q)^swz
  const int frow = lane & 15;
  const int q    = lane >> 4;
  const int swz  = frow & 7;
  const int aro  = (wm + frow) * BKH;
  const int bro  = (wn + frow) * BKH;

  for (int k0 = 0; k0 < K; k0 += BKH) {
#pragma unroll
    for (int p = 0; p < 4; ++p) {
      async_cp16(ga + (long)(p * 32) * K + k0, la + p * 2048);
      async_cp16(gb + (long)(p * 32) * K + k0, lb + p * 2048);
    }
    __syncthreads();
#pragma unroll
    for (int s = 0; s < 2; ++s) {
      const int co = ((s * 4 + q) ^ swz) * 8;
      f16x8 af[4], bf[4];
#pragma unroll
      for (int i = 0; i < 4; ++i) af[i] = *(const f16x8*)&lA[aro + i * 1024 + co];
#pragma unroll
      for (int j = 0; j < 4; ++j) bf[j] = *(const f16x8*)&lB[bro + j * 1024 + co];
#pragma unroll
      for (int i = 0; i < 4; ++i)
#pragma unroll
        for (int j = 0; j < 4; ++j)
          acc[i][j] = SWAP
            ? __builtin_amdgcn_mfma_f32_16x16x32_f16(bf[j], af[i], acc[i][j], 0, 0, 0)
            : __builtin_amdgcn_mfma_f32_16x16x32_f16(af[i], bf[j], acc[i][j], 0, 0, 0);
    }
    __syncthreads();   // frag reads done before next stage overwrites
  }

  const int TS = 136;  // f16 epilogue tile stride (halfs)

  if constexpr (MODE == 0 || MODE == 1) {
    f16* T = (f16*)smem;   // [128][TS]
    float rs[4] = {0.f, 0.f, 0.f, 0.f};
    const float sc = (MODE == 0 && z == 0) ? scale : 1.0f;
#pragma unroll
    for (int i = 0; i < 4; ++i)
#pragma unroll
      for (int j = 0; j < 4; ++j) {
        f16x4 v;
#pragma unroll
        for (int r = 0; r < 4; ++r) {
          float xv = acc[i][j][r];
          if (MODE == 1) xv = __expf(xv); else xv *= sc;
          v[r] = (f16)xv;
          if (MODE == 1) rs[i] += (float)v[r];   // sum of f16-rounded values
        }
        *(f16x4*)&T[(wm + i * 16 + frow) * TS + wn + j * 16 + q * 4] = v;
      }
    if constexpr (MODE == 1) {
#pragma unroll
      for (int i = 0; i < 4; ++i) {
        rs[i] += __shfl_xor(rs[i], 16);
        rs[i] += __shfl_xor(rs[i], 32);   // full 64-col segment sum
      }
      if (lane < 16) {   // q==0 lanes hold the reduced sums
        float* rp = Rsum + ((long)z * 32 + blockIdx.y * 2 + (wn >> 6)) * SEQ + m0 + wm;
#pragma unroll
        for (int i = 0; i < 4; ++i) rp[i * 16 + frow] = rs[i];
      }
    }
    __syncthreads();
    f16* C = (f16*)Cbase + (long)z * sCz;
    const int row = tid >> 1, seg = (tid & 1) * 64;
#pragma unroll
    for (int k = 0; k < 8; ++k) {
      f16x8 v = *(const f16x8*)&T[row * TS + seg + k * 8];
      *(f16x8*)&C[(long)(m0 + row) * N + n0 + seg + k * 8] = v;
    }
  }

  if constexpr (MODE == 3) {   // Vt[b][d][s]; SWAP=false: regs = consecutive m (=s)
    f16* T = (f16*)smem;       // [n(=d) 128][TS] holding m(=s) contiguous
#pragma unroll
    for (int i = 0; i < 4; ++i)
#pragma unroll
      for (int j = 0; j < 4; ++j) {
        f16x4 v = {(f16)acc[i][j][0], (f16)acc[i][j][1],
                   (f16)acc[i][j][2], (f16)acc[i][j][3]};
        *(f16x4*)&T[(wn + j * 16 + frow) * TS + wm + i * 16 + q * 4] = v;
      }
    __syncthreads();
    f16* C = (f16*)Cbase;
    const int b = m0 >> 11, sl = m0 & 2047;
    const int row = tid >> 1, seg = (tid & 1) * 64;
#pragma unroll
    for (int k = 0; k < 8; ++k) {
      f16x8 v = *(const f16x8*)&T[row * TS + seg + k * 8];
      *(f16x8*)&C[(long)b * QB + (long)(n0 + row) * SEQ + sl + seg + k * 8] = v;
    }
  }

  if constexpr (MODE == 2) {   // fp32 out, normalized; 2-pass (64 rows) epilogue
    float inv[4];
#pragma unroll
    for (int i = 0; i < 4; ++i) inv[i] = sinv[wm + i * 16 + frow];

    float* Tf = (float*)smem;   // [64][FS] fp32
    const int FS = 132;
    float* C = (float*)Cbase + (long)z * sCz;
    for (int pass = 0; pass < 2; ++pass) {
      if (wm == pass * 64) {
#pragma unroll
        for (int i = 0; i < 4; ++i)
#pragma unroll
          for (int j = 0; j < 4; ++j) {
            f32x4 v = acc[i][j] * inv[i];
            *(f32x4*)&Tf[(i * 16 + frow) * FS + wn + j * 16 + q * 4] = v;
          }
      }
      __syncthreads();
      const int row = tid >> 2, cs = (tid & 3) * 32;
#pragma unroll
      for (int k = 0; k < 8; ++k) {
        f32x4 v = *(const f32x4*)&Tf[row * FS + cs + k * 4];
        *(f32x4*)&C[(long)(m0 + pass * 64 + row) * N + n0 + cs + k * 4] = v;
      }
      if (pass == 0) __syncthreads();
    }
  }
}

extern "C" void kernel_launch(void* const* d_in, const int* in_sizes, int n_in,
                              void* d_out, int out_size, void* d_ws, size_t ws_size,
                              hipStream_t stream) {
  const float* x  = (const float*)d_in[0];
  const float* Wq = (const float*)d_in[1];
  const float* Wk = (const float*)d_in[2];
  const float* Wv = (const float*)d_in[3];

  f16* ws    = (f16*)d_ws;
  f16* x16   = ws;                  // XN
  f16* Wv16  = x16 + XN;            // WN
  f16* WqT16 = Wv16 + WN;           // WN
  f16* WkT16 = WqT16 + WN;          // WN
  f16* G2    = WkT16 + WN;          // WN   G2[e][d] = sum_k Wk[k][e]Wq[k][d] * scale
  f16* T16   = G2 + WN;             // XN   T~ = x @ G2^T
  f16* Vt16  = T16 + XN;            // XN   [b][d][s]
  f16* S16   = Vt16 + XN;           // NBAT*SB (exp scores, unnormalized)
  float* rsumP = (float*)(S16 + (long)NBAT * SB);   // [8][32][2048] partials

  cvt_all<<<(XN4 + WN4) / 256, 256, 0, stream>>>(x, Wv, x16, Wv16);
  transpose_w<<<dim3(24, 24, 2), 256, 0, stream>>>(Wq, Wk, WqT16, WkT16);

  dim3 blk(256);
  // G2 = NT(WkT, WqT) * 1/sqrt(768)  (768x768x768)
  gemm_nt<0, true><<<dim3(6, 6, 1), blk, 0, stream>>>(
      WkT16, 0L, WqT16, 0L, (void*)G2, 0L, nullptr, DIM, DIM, 0.03608439182435161f);
  // T~ = NT(x16, G2)  (16384x768x768)
  gemm_nt<0, true><<<dim3(MTOT / BM, DIM / BN, 1), blk, 0, stream>>>(
      x16, 0L, G2, 0L, (void*)T16, 0L, nullptr, DIM, DIM, 1.0f);
  // Vt = (x @ Wv^T)^T per batch  (16384x768x768, transposed out)
  gemm_nt<3, false><<<dim3(MTOT / BM, DIM / BN, 1), blk, 0, stream>>>(
      x16, 0L, Wv16, 0L, (void*)Vt16, 0L, nullptr, DIM, DIM, 1.0f);
  // P' = exp(T~ x^T) per batch + rowsum partials  (2048x2048x768 x8)
  gemm_nt<1, true><<<dim3(SEQ / BM, SEQ / BN, NBAT), blk, 0, stream>>>(
      T16, QB, x16, QB, (void*)S16, SB, rsumP, SEQ, DIM, 1.0f);
  // H = (P' @ Vt^T) / rowsum, fp32  (2048x768x2048 x8)
  gemm_nt<2, true><<<dim3(SEQ / BM, DIM / BN, NBAT), blk, 0, stream>>>(
      S16, SB, Vt16, QB, d_out, QB, rsumP, DIM, SEQ, 1.0f);
}